// Round 12
// baseline (188.834 us; speedup 1.0000x reference)
//
#include <hip/hip_runtime.h>
#include <hip/hip_fp16.h>
#include <math.h>

#define N_RADIAL 8
#define N_PSEUDO 4
#define EMB_DIM 32
#define CUTOFF 5.0f
#define WIDTH 0.5f
#define SQRT3_4PI 0.48860251190291992f   /* sqrt(3/(4*pi)) */
#define INV_SQRT2 0.70710678118654752f
#define PI_F 3.14159265358979323846f

#define SLICE_SHIFT 7
#define SLICE_SZ 128            /* atoms per slice */
#define MAX_NSLICE 2048         /* LDS histogram capacity */
#define HIST_EPB 4096           /* edges per block, hist pass (centers only) */
#define SCAT_EPB 4096           /* edges per block, scatter pass */
#define SCAT_THREADS 1024
#define SCAT_ITER (SCAT_EPB / SCAT_THREADS)   /* 4: register payload stash */
#define ACC_THREADS 1024

// ---------------------------------------------------------------------------
// G[tc][tn][n][k], k=0,1 only (v[:,:,2] is discarded by the reference).
// ---------------------------------------------------------------------------
__global__ void build_G_kernel(const float* __restrict__ W_species, // (4,4)
                               const float* __restrict__ Emb,       // (4,32)
                               const float* __restrict__ Wc,        // (32,3)
                               float* __restrict__ G) {
    int i = threadIdx.x;            // 256 threads, one per table entry
    int k  = i & 1;
    int n  = (i >> 1) & 7;
    int tn = (i >> 4) & 3;
    int tc = i >> 6;
    float acc = 0.0f;
    #pragma unroll
    for (int q = 0; q < N_PSEUDO; ++q) {
        int d = n * N_PSEUDO + q;
        acc += W_species[tn * N_PSEUDO + q] * Emb[tc * EMB_DIM + d] * Wc[d * 3 + k];
    }
    G[i] = acc;
}

// ---------------------------------------------------------------------------
// Per-edge math with NATIVE trig (v_sin/v_cos; theta = pi*r/5 < pi, no range
// reduction needed; fcut arg pi*t <= pi). Returns false if cut off.
// pr[j] = Y[m]*s[k] m-major: (Y0s0,Y0s1,Y1s0,Y1s1,Y2s0,Y2s1)
// ---------------------------------------------------------------------------
__device__ __forceinline__ bool edge_products(float vx, float vy, float vz,
                                              const float* __restrict__ Gp,
                                              float pr[6]) {
    float r = sqrtf(vx * vx + vy * vy + vz * vz);
    if (r >= CUTOFF) return false;

    float rinv = 1.0f / (r + 1e-10f);

    float t = fminf(fmaxf((r - (CUTOFF - WIDTH)) * (1.0f / WIDTH), 0.0f), 1.0f);
    float fcut = 0.5f * (1.0f + __cosf(PI_F * t));

    float theta = (PI_F / CUTOFF) * r;
    float s1 = __sinf(theta);
    float c1 = __cosf(theta);
    float twoc  = 2.0f * c1;
    float sn_m1 = 0.0f;
    float sn    = s1;

    float s0 = 0.0f, s1a = 0.0f;
    #pragma unroll
    for (int n = 0; n < N_RADIAL; ++n) {
        s0  = fmaf(sn, Gp[n * 2 + 0], s0);
        s1a = fmaf(sn, Gp[n * 2 + 1], s1a);
        float nxt = twoc * sn - sn_m1;
        sn_m1 = sn;
        sn = nxt;
    }
    float coef = rinv * fcut;
    s0 *= coef; s1a *= coef;

    float Y0 = SQRT3_4PI * vy * rinv;
    float Y1 = SQRT3_4PI * vz * rinv;
    float Y2 = SQRT3_4PI * vx * rinv;

    pr[0] = Y0 * s0; pr[1] = Y0 * s1a;
    pr[2] = Y1 * s0; pr[3] = Y1 * s1a;
    pr[4] = Y2 * s0; pr[5] = Y2 * s1a;
    return true;
}

// ---------------------------------------------------------------------------
// Pass 1: count ALL edges per slice (centers only). Over-counts vs the pass
// predicate — sliceStart just reserves capacity; scatter packs from the start.
// ---------------------------------------------------------------------------
__global__ __launch_bounds__(256)
void hist_kernel(const int* __restrict__ centers,
                 unsigned int* __restrict__ ghist, int E, int nslice) {
    __shared__ unsigned int hist[MAX_NSLICE];
    for (int i = threadIdx.x; i < nslice; i += blockDim.x) hist[i] = 0u;
    __syncthreads();

    int beg = blockIdx.x * HIST_EPB;
    int end = min(beg + HIST_EPB, E);
    for (int e = beg + (int)threadIdx.x; e < end; e += (int)blockDim.x)
        atomicAdd(&hist[centers[e] >> SLICE_SHIFT], 1u);
    __syncthreads();

    for (int i = threadIdx.x; i < nslice; i += blockDim.x)
        if (hist[i]) atomicAdd(&ghist[i], hist[i]);
}

// ---------------------------------------------------------------------------
// Pass 2: exclusive scan on one 64-lane wave (chunked serial + shfl wave-scan).
// ---------------------------------------------------------------------------
__global__ void scan_kernel(const unsigned int* __restrict__ ghist,
                            unsigned int* __restrict__ sliceStart,
                            unsigned int* __restrict__ cursor, int nslice) {
    int lane = (int)threadIdx.x;        // 64 threads
    int chunk = (nslice + 63) / 64;
    int lo = lane * chunk;
    int hi = min(lo + chunk, nslice);

    unsigned int sum = 0;
    for (int i = lo; i < hi; ++i) sum += ghist[i];

    unsigned int inc = sum;
    #pragma unroll
    for (int d = 1; d < 64; d <<= 1) {
        unsigned int o = __shfl_up(inc, d, 64);
        if (lane >= d) inc += o;
    }
    unsigned int run = inc - sum;       // exclusive prefix of this chunk

    for (int i = lo; i < hi; ++i) {
        sliceStart[i] = run;
        cursor[i]     = run;
        run += ghist[i];
    }
    if (lane == 63) sliceStart[nslice] = run;   // grand total
}

// ---------------------------------------------------------------------------
// Pass 3: single-read scatter. Count pass stashes the 8B encoded payload
// (f16 vx,vy,vz + u16 meta{lid|tc<<7|tn<<9}) in REGISTERS (static #pragma
// unroll indexing), reserves cursor ranges, then NON-TEMPORAL stores — the
// payload never dirties L2, so accum inherits no cross-XCD flush.
// ---------------------------------------------------------------------------
__global__ __launch_bounds__(SCAT_THREADS)
void scatter_kernel(const float* __restrict__ vecs,
                    const int*   __restrict__ centers,
                    const int*   __restrict__ neighbors,
                    const int*   __restrict__ species,
                    unsigned int* __restrict__ cursor,
                    unsigned long long* __restrict__ payload, // 8B per entry
                    int E, int nslice) {
    __shared__ unsigned int hist[MAX_NSLICE];
    for (int i = threadIdx.x; i < nslice; i += blockDim.x) hist[i] = 0u;
    __syncthreads();

    int beg = blockIdx.x * SCAT_EPB;
    int end = min(beg + SCAT_EPB, E);

    unsigned long long word[SCAT_ITER];
    int sl[SCAT_ITER];

    // single read pass: predicate on r^2 (no sqrt), encode, LDS count
    #pragma unroll
    for (int k = 0; k < SCAT_ITER; ++k) {
        sl[k] = -1;
        word[k] = 0;
        int e = beg + k * SCAT_THREADS + (int)threadIdx.x;
        if (e < end) {
            float vx = vecs[3 * e + 0], vy = vecs[3 * e + 1], vz = vecs[3 * e + 2];
            float r2 = vx * vx + vy * vy + vz * vz;
            if (r2 < CUTOFF * CUTOFF) {
                int c = centers[e];
                unsigned int tc = (unsigned int)species[c];
                unsigned int tn = (unsigned int)species[neighbors[e]];
                unsigned int meta = (unsigned int)(c & (SLICE_SZ - 1)) | (tc << 7) | (tn << 9);
                unsigned int hx = (unsigned int)__half_as_ushort(__float2half(vx));
                unsigned int hy = (unsigned int)__half_as_ushort(__float2half(vy));
                unsigned int hz = (unsigned int)__half_as_ushort(__float2half(vz));
                unsigned int lo = hx | (hy << 16);
                unsigned int hi = hz | (meta << 16);
                word[k] = ((unsigned long long)hi << 32) | lo;
                sl[k] = c >> SLICE_SHIFT;
                atomicAdd(&hist[sl[k]], 1u);
            }
        }
    }
    __syncthreads();

    // reserve global ranges; hist[s] becomes this block's running cursor
    for (int s = threadIdx.x; s < nslice; s += (int)blockDim.x) {
        unsigned int c = hist[s];
        hist[s] = c ? atomicAdd(&cursor[s], c) : 0u;
    }
    __syncthreads();

    // placement from registers, non-temporal 8B stores
    #pragma unroll
    for (int k = 0; k < SCAT_ITER; ++k) {
        if (sl[k] >= 0) {
            unsigned int pos = atomicAdd(&hist[sl[k]], 1u);
            __builtin_nontemporal_store(word[k], payload + pos);
        }
    }
}

// ---------------------------------------------------------------------------
// Pass 4: one block per slice. Non-temporal contiguous 8B reads, f16 decode,
// native-trig math, LDS f32 atomics (stride 9), cross-product epilogue.
// ---------------------------------------------------------------------------
__global__ __launch_bounds__(ACC_THREADS)
void accum_kernel(const unsigned long long* __restrict__ payload,
                  const unsigned int* __restrict__ sliceStart,
                  const unsigned int* __restrict__ cursor,   // final = packed end
                  const float* __restrict__ G,
                  float* __restrict__ out, int A) {
    __shared__ float Gs[256];
    __shared__ float acc[SLICE_SZ * 9];
    int s = blockIdx.x;

    if (threadIdx.x < 256) Gs[threadIdx.x] = G[threadIdx.x];
    for (int i = threadIdx.x; i < SLICE_SZ * 9; i += blockDim.x) acc[i] = 0.0f;
    __syncthreads();

    unsigned int beg = sliceStart[s], end = cursor[s];
    for (unsigned int i = beg + threadIdx.x; i < end; i += blockDim.x) {
        unsigned long long w = __builtin_nontemporal_load(payload + i);
        unsigned int lo = (unsigned int)w;
        unsigned int hi = (unsigned int)(w >> 32);
        float vx = __half2float(__ushort_as_half((unsigned short)(lo & 0xffffu)));
        float vy = __half2float(__ushort_as_half((unsigned short)(lo >> 16)));
        float vz = __half2float(__ushort_as_half((unsigned short)(hi & 0xffffu)));
        unsigned int meta = hi >> 16;
        int lid = (int)(meta & (SLICE_SZ - 1));
        int tc  = (int)((meta >> 7) & 3);
        int tn  = (int)((meta >> 9) & 3);
        const float* Gp = &Gs[((tc * 4 + tn) * 8) * 2];

        float pr[6];
        if (!edge_products(vx, vy, vz, Gp, pr)) continue;  // f16-boundary: fcut~0

        float* ap = &acc[lid * 9];
        atomicAdd(ap + 0, pr[0]);
        atomicAdd(ap + 1, pr[1]);
        atomicAdd(ap + 2, pr[2]);
        atomicAdd(ap + 3, pr[3]);
        atomicAdd(ap + 4, pr[4]);
        atomicAdd(ap + 5, pr[5]);
    }
    __syncthreads();

    int a = s * SLICE_SZ + (int)threadIdx.x;
    if (threadIdx.x < SLICE_SZ && a < A) {
        const float* v = &acc[threadIdx.x * 9];
        float a0 = v[0], b0 = v[1];   // m=0 (y)
        float a1 = v[2], b1 = v[3];   // m=1 (z)
        float a2 = v[4], b2 = v[5];   // m=2 (x)

        float c0 = (a1 * b2 - a2 * b1) * INV_SQRT2;
        float c1 = (a2 * b0 - a0 * b2) * INV_SQRT2;
        float c2 = (a0 * b1 - a1 * b0) * INV_SQRT2;

        float* o = out + (size_t)a * 9;
        o[0] = a0; o[1] = b0; o[2] = c0;
        o[3] = a1; o[4] = b1; o[5] = c1;
        o[6] = a2; o[7] = b2; o[8] = c2;
    }
}

// ===========================================================================
// Fallback path (Round 6): packed fixed-point u64 global atomics. Used only
// if the workspace can't hold the sort payload.
// ===========================================================================
#define Q_INV 8192.0f
#define Q 1.220703125e-4
#define BIAS_ENC 131072.0f
#define ENC_MAX 262143.0f
#define FIELD_MASK 0x3FFFFFFULL

__global__ void edge_kernel_fb(const float* __restrict__ vecs,
                               const int* __restrict__ centers,
                               const int* __restrict__ neighbors,
                               const int* __restrict__ species,
                               const float* __restrict__ G,
                               unsigned long long* __restrict__ vacc, int E) {
    __shared__ float Gs[256];
    Gs[threadIdx.x] = G[threadIdx.x];
    __syncthreads();

    int e = blockIdx.x * blockDim.x + threadIdx.x;
    if (e >= E) return;

    float vx = vecs[3 * e + 0], vy = vecs[3 * e + 1], vz = vecs[3 * e + 2];
    int c = centers[e];
    int tc = species[c];
    int tn = species[neighbors[e]];
    const float* Gp = &Gs[((tc * 4 + tn) * 8) * 2];

    float pr[6];
    if (!edge_products(vx, vy, vz, Gp, pr)) return;

    unsigned long long* base = vacc + (size_t)c * 4;
    #pragma unroll
    for (int j = 0; j < 3; ++j) {
        float el = fminf(fmaxf(fmaf(pr[2 * j + 0], Q_INV, BIAS_ENC) + 0.5f, 0.0f), ENC_MAX);
        float eh = fminf(fmaxf(fmaf(pr[2 * j + 1], Q_INV, BIAS_ENC) + 0.5f, 0.0f), ENC_MAX);
        unsigned long long w = (1ULL << 52)
                             | ((unsigned long long)(unsigned int)eh << 26)
                             | (unsigned long long)(unsigned int)el;
        atomicAdd(base + j, w);
    }
}

__global__ void finalize_fb(const unsigned long long* __restrict__ vacc,
                            float* __restrict__ out, int A) {
    int a = blockIdx.x * blockDim.x + threadIdx.x;
    if (a >= A) return;

    const unsigned long long* w = vacc + (size_t)a * 4;
    double v[6];
    #pragma unroll
    for (int j = 0; j < 3; ++j) {
        unsigned long long x = w[j];
        double n = (double)(x >> 52);
        v[2 * j + 0] = (double)(x & FIELD_MASK)         * (double)Q - n * 16.0;
        v[2 * j + 1] = (double)((x >> 26) & FIELD_MASK) * (double)Q - n * 16.0;
    }
    float a0 = (float)v[0], b0 = (float)v[1];
    float a1 = (float)v[2], b1 = (float)v[3];
    float a2 = (float)v[4], b2 = (float)v[5];
    float c0 = (a1 * b2 - a2 * b1) * INV_SQRT2;
    float c1 = (a2 * b0 - a0 * b2) * INV_SQRT2;
    float c2 = (a0 * b1 - a1 * b0) * INV_SQRT2;
    float* o = out + (size_t)a * 9;
    o[0] = a0; o[1] = b0; o[2] = c0;
    o[3] = a1; o[4] = b1; o[5] = c1;
    o[6] = a2; o[7] = b2; o[8] = c2;
}

extern "C" void kernel_launch(void* const* d_in, const int* in_sizes, int n_in,
                              void* d_out, int out_size, void* d_ws, size_t ws_size,
                              hipStream_t stream) {
    const float* vecs      = (const float*)d_in[0];
    const float* W_species = (const float*)d_in[1];
    const float* Emb       = (const float*)d_in[2];
    const float* Wc        = (const float*)d_in[3];
    const int*   centers   = (const int*)d_in[4];
    const int*   neighbors = (const int*)d_in[5];
    const int*   species   = (const int*)d_in[6];

    int E = in_sizes[0] / 3;
    int A = in_sizes[6];

    int nslice = (A + SLICE_SZ - 1) / SLICE_SZ;

    // Workspace layout (sort path): payload | ghist | sliceStart | cursor | G
    size_t payloadBytes = (size_t)E * 8;   // 8B per entry
    size_t metaBytes    = (size_t)(3 * nslice + 1 + 256) * sizeof(float) + 256;
    bool sort_path = (nslice <= MAX_NSLICE) && (ws_size >= payloadBytes + metaBytes);

    if (sort_path) {
        unsigned long long* payload = (unsigned long long*)d_ws;
        unsigned int* ghist      = (unsigned int*)((char*)d_ws + payloadBytes);
        unsigned int* sliceStart = ghist + nslice;
        unsigned int* cursor     = sliceStart + (nslice + 1);
        float*        G          = (float*)(cursor + nslice);

        (void)hipMemsetAsync(ghist, 0, (size_t)nslice * sizeof(unsigned int), stream);
        build_G_kernel<<<1, 256, 0, stream>>>(W_species, Emb, Wc, G);

        int nbh = (E + HIST_EPB - 1) / HIST_EPB;
        hist_kernel<<<nbh, 256, 0, stream>>>(centers, ghist, E, nslice);
        scan_kernel<<<1, 64, 0, stream>>>(ghist, sliceStart, cursor, nslice);
        int nbs = (E + SCAT_EPB - 1) / SCAT_EPB;
        scatter_kernel<<<nbs, SCAT_THREADS, 0, stream>>>(
            vecs, centers, neighbors, species, cursor, payload, E, nslice);
        accum_kernel<<<nslice, ACC_THREADS, 0, stream>>>(
            payload, sliceStart, cursor, G, (float*)d_out, A);
    } else {
        unsigned long long* vacc = (unsigned long long*)d_ws;  // (A,4)
        float* G = (float*)(vacc + (size_t)A * 4);
        (void)hipMemsetAsync(vacc, 0, (size_t)A * 4 * sizeof(unsigned long long), stream);
        build_G_kernel<<<1, 256, 0, stream>>>(W_species, Emb, Wc, G);
        const int threads = 256;
        edge_kernel_fb<<<(E + threads - 1) / threads, threads, 0, stream>>>(
            vecs, centers, neighbors, species, G, vacc, E);
        finalize_fb<<<(A + threads - 1) / threads, threads, 0, stream>>>(
            vacc, (float*)d_out, A);
    }
}

// Round 13
// 77.923 us; speedup vs baseline: 2.4233x; 2.4233x over previous
//
#include <hip/hip_runtime.h>
#include <hip/hip_fp16.h>
#include <math.h>

#define N_RADIAL 8
#define N_PSEUDO 4
#define EMB_DIM 32
#define CUTOFF 5.0f
#define WIDTH 0.5f
#define SQRT3_4PI 0.48860251190291992f   /* sqrt(3/(4*pi)) */
#define INV_SQRT2 0.70710678118654752f
#define PI_F 3.14159265358979323846f

#define SLICE_SHIFT 7
#define SLICE_SZ 128            /* atoms per slice */
#define MAX_NSLICE 2048         /* LDS histogram capacity */
#define HIST_EPB 4096           /* edges per block, hist pass (centers only) */
#define SCAT_EPB 4096           /* edges per block, scatter pass */
#define SCAT_THREADS 1024
#define SCAT_ITER (SCAT_EPB / SCAT_THREADS)   /* 4: register payload stash */
#define ACC_THREADS 1024

/* Fixed-point packing (Round-6 proven): q=2^-13, bias 16.
   word = [count:12 | e_hi:26 | e_lo:26]; per-edge add is non-negative in
   every field -> no cross-field carries; capacity 4096 edges/atom. */
#define Q_INV 8192.0f
#define Q 1.220703125e-4
#define BIAS_ENC 131072.0f
#define ENC_MAX 262143.0f
#define FIELD_MASK 0x3FFFFFFULL

// ---------------------------------------------------------------------------
// G[tc][tn][n][k], k=0,1 only (v[:,:,2] is discarded by the reference).
// ---------------------------------------------------------------------------
__global__ void build_G_kernel(const float* __restrict__ W_species, // (4,4)
                               const float* __restrict__ Emb,       // (4,32)
                               const float* __restrict__ Wc,        // (32,3)
                               float* __restrict__ G) {
    int i = threadIdx.x;            // 256 threads, one per table entry
    int k  = i & 1;
    int n  = (i >> 1) & 7;
    int tn = (i >> 4) & 3;
    int tc = i >> 6;
    float acc = 0.0f;
    #pragma unroll
    for (int q = 0; q < N_PSEUDO; ++q) {
        int d = n * N_PSEUDO + q;
        acc += W_species[tn * N_PSEUDO + q] * Emb[tc * EMB_DIM + d] * Wc[d * 3 + k];
    }
    G[i] = acc;
}

// ---------------------------------------------------------------------------
// Per-edge math, native trig (theta < pi: no range reduction needed).
// pr[j] = Y[m]*s[k] m-major: (Y0s0,Y0s1,Y1s0,Y1s1,Y2s0,Y2s1)
// ---------------------------------------------------------------------------
__device__ __forceinline__ bool edge_products(float vx, float vy, float vz,
                                              const float* __restrict__ Gp,
                                              float pr[6]) {
    float r = sqrtf(vx * vx + vy * vy + vz * vz);
    if (r >= CUTOFF) return false;

    float rinv = 1.0f / (r + 1e-10f);

    float t = fminf(fmaxf((r - (CUTOFF - WIDTH)) * (1.0f / WIDTH), 0.0f), 1.0f);
    float fcut = 0.5f * (1.0f + __cosf(PI_F * t));

    float theta = (PI_F / CUTOFF) * r;
    float s1 = __sinf(theta);
    float c1 = __cosf(theta);
    float twoc  = 2.0f * c1;
    float sn_m1 = 0.0f;
    float sn    = s1;

    float s0 = 0.0f, s1a = 0.0f;
    #pragma unroll
    for (int n = 0; n < N_RADIAL; ++n) {
        s0  = fmaf(sn, Gp[n * 2 + 0], s0);
        s1a = fmaf(sn, Gp[n * 2 + 1], s1a);
        float nxt = twoc * sn - sn_m1;
        sn_m1 = sn;
        sn = nxt;
    }
    float coef = rinv * fcut;
    s0 *= coef; s1a *= coef;

    float Y0 = SQRT3_4PI * vy * rinv;
    float Y1 = SQRT3_4PI * vz * rinv;
    float Y2 = SQRT3_4PI * vx * rinv;

    pr[0] = Y0 * s0; pr[1] = Y0 * s1a;
    pr[2] = Y1 * s0; pr[3] = Y1 * s1a;
    pr[4] = Y2 * s0; pr[5] = Y2 * s1a;
    return true;
}

// ---------------------------------------------------------------------------
// Pass 1: count ALL edges per slice (centers only). Over-counts vs the pass
// predicate — sliceStart just reserves capacity.
// ---------------------------------------------------------------------------
__global__ __launch_bounds__(256)
void hist_kernel(const int* __restrict__ centers,
                 unsigned int* __restrict__ ghist, int E, int nslice) {
    __shared__ unsigned int hist[MAX_NSLICE];
    for (int i = threadIdx.x; i < nslice; i += blockDim.x) hist[i] = 0u;
    __syncthreads();

    int beg = blockIdx.x * HIST_EPB;
    int end = min(beg + HIST_EPB, E);
    for (int e = beg + (int)threadIdx.x; e < end; e += (int)blockDim.x)
        atomicAdd(&hist[centers[e] >> SLICE_SHIFT], 1u);
    __syncthreads();

    for (int i = threadIdx.x; i < nslice; i += blockDim.x)
        if (hist[i]) atomicAdd(&ghist[i], hist[i]);
}

// ---------------------------------------------------------------------------
// Pass 2: exclusive scan on one 64-lane wave (chunked serial + shfl wave-scan).
// ---------------------------------------------------------------------------
__global__ void scan_kernel(const unsigned int* __restrict__ ghist,
                            unsigned int* __restrict__ sliceStart,
                            unsigned int* __restrict__ cursor, int nslice) {
    int lane = (int)threadIdx.x;        // 64 threads
    int chunk = (nslice + 63) / 64;
    int lo = lane * chunk;
    int hi = min(lo + chunk, nslice);

    unsigned int sum = 0;
    for (int i = lo; i < hi; ++i) sum += ghist[i];

    unsigned int inc = sum;
    #pragma unroll
    for (int d = 1; d < 64; d <<= 1) {
        unsigned int o = __shfl_up(inc, d, 64);
        if (lane >= d) inc += o;
    }
    unsigned int run = inc - sum;       // exclusive prefix of this chunk

    for (int i = lo; i < hi; ++i) {
        sliceStart[i] = run;
        cursor[i]     = run;
        run += ghist[i];
    }
    if (lane == 63) sliceStart[nslice] = run;   // grand total
}

// ---------------------------------------------------------------------------
// Pass 3: single-read scatter. Registers stash the 8B encoded payload
// (f16 vx,vy,vz + u16 meta{lid|tc<<7|tn<<9}); NORMAL stores (Round-12 nt
// experiment: nt 8B scatter = 46B/store fabric writes, REVERTED — L2 merges
// neighboring payload writes far better).
// ---------------------------------------------------------------------------
__global__ __launch_bounds__(SCAT_THREADS)
void scatter_kernel(const float* __restrict__ vecs,
                    const int*   __restrict__ centers,
                    const int*   __restrict__ neighbors,
                    const int*   __restrict__ species,
                    unsigned int* __restrict__ cursor,
                    unsigned long long* __restrict__ payload, // 8B per entry
                    int E, int nslice) {
    __shared__ unsigned int hist[MAX_NSLICE];
    for (int i = threadIdx.x; i < nslice; i += blockDim.x) hist[i] = 0u;
    __syncthreads();

    int beg = blockIdx.x * SCAT_EPB;
    int end = min(beg + SCAT_EPB, E);

    unsigned long long word[SCAT_ITER];
    int sl[SCAT_ITER];

    // single read pass: predicate on r^2 (no sqrt), encode, LDS count
    #pragma unroll
    for (int k = 0; k < SCAT_ITER; ++k) {
        sl[k] = -1;
        word[k] = 0;
        int e = beg + k * SCAT_THREADS + (int)threadIdx.x;
        if (e < end) {
            float vx = vecs[3 * e + 0], vy = vecs[3 * e + 1], vz = vecs[3 * e + 2];
            float r2 = vx * vx + vy * vy + vz * vz;
            if (r2 < CUTOFF * CUTOFF) {
                int c = centers[e];
                unsigned int tc = (unsigned int)species[c];
                unsigned int tn = (unsigned int)species[neighbors[e]];
                unsigned int meta = (unsigned int)(c & (SLICE_SZ - 1)) | (tc << 7) | (tn << 9);
                unsigned int hx = (unsigned int)__half_as_ushort(__float2half(vx));
                unsigned int hy = (unsigned int)__half_as_ushort(__float2half(vy));
                unsigned int hz = (unsigned int)__half_as_ushort(__float2half(vz));
                unsigned int lo = hx | (hy << 16);
                unsigned int hi = hz | (meta << 16);
                word[k] = ((unsigned long long)hi << 32) | lo;
                sl[k] = c >> SLICE_SHIFT;
                atomicAdd(&hist[sl[k]], 1u);
            }
        }
    }
    __syncthreads();

    // reserve global ranges; hist[s] becomes this block's running cursor
    for (int s = threadIdx.x; s < nslice; s += (int)blockDim.x) {
        unsigned int c = hist[s];
        hist[s] = c ? atomicAdd(&cursor[s], c) : 0u;
    }
    __syncthreads();

    // placement from registers, normal 8B stores (L2-merged)
    #pragma unroll
    for (int k = 0; k < SCAT_ITER; ++k) {
        if (sl[k] >= 0) {
            unsigned int pos = atomicAdd(&hist[sl[k]], 1u);
            payload[pos] = word[k];
        }
    }
}

// ---------------------------------------------------------------------------
// Pass 4: one block per slice. Contiguous 8B reads, f16 decode, native-trig
// math, then 3 u64 INTEGER LDS atomics per edge (ds_add_u64 — unconditionally
// native) carrying bias/fixed-point-encoded (pr_lo, pr_hi) pairs + edge count.
// Replaces 6 f32 LDS atomics (suspected serialized/CAS path, the constant
// ~84us across Rounds 8-12). Decode + cross product in epilogue.
// ---------------------------------------------------------------------------
__global__ __launch_bounds__(ACC_THREADS)
void accum_kernel(const unsigned long long* __restrict__ payload,
                  const unsigned int* __restrict__ sliceStart,
                  const unsigned int* __restrict__ cursor,   // final = packed end
                  const float* __restrict__ G,
                  float* __restrict__ out, int A) {
    __shared__ float Gs[256];
    __shared__ unsigned long long acc64[SLICE_SZ * 3];
    int s = blockIdx.x;

    if (threadIdx.x < 256) Gs[threadIdx.x] = G[threadIdx.x];
    for (int i = threadIdx.x; i < SLICE_SZ * 3; i += blockDim.x) acc64[i] = 0ull;
    __syncthreads();

    unsigned int beg = sliceStart[s], end = cursor[s];
    for (unsigned int i = beg + threadIdx.x; i < end; i += blockDim.x) {
        unsigned long long w = payload[i];
        unsigned int lo = (unsigned int)w;
        unsigned int hi = (unsigned int)(w >> 32);
        float vx = __half2float(__ushort_as_half((unsigned short)(lo & 0xffffu)));
        float vy = __half2float(__ushort_as_half((unsigned short)(lo >> 16)));
        float vz = __half2float(__ushort_as_half((unsigned short)(hi & 0xffffu)));
        unsigned int meta = hi >> 16;
        int lid = (int)(meta & (SLICE_SZ - 1));
        int tc  = (int)((meta >> 7) & 3);
        int tn  = (int)((meta >> 9) & 3);
        const float* Gp = &Gs[((tc * 4 + tn) * 8) * 2];

        float pr[6];
        if (!edge_products(vx, vy, vz, Gp, pr)) continue;  // f16-boundary: fcut~0

        unsigned long long* ap = &acc64[lid * 3];
        #pragma unroll
        for (int j = 0; j < 3; ++j) {
            float el = fminf(fmaxf(fmaf(pr[2 * j + 0], Q_INV, BIAS_ENC) + 0.5f, 0.0f), ENC_MAX);
            float eh = fminf(fmaxf(fmaf(pr[2 * j + 1], Q_INV, BIAS_ENC) + 0.5f, 0.0f), ENC_MAX);
            unsigned long long wrd = (1ULL << 52)
                                   | ((unsigned long long)(unsigned int)eh << 26)
                                   | (unsigned long long)(unsigned int)el;
            atomicAdd(ap + j, wrd);
        }
    }
    __syncthreads();

    int a = s * SLICE_SZ + (int)threadIdx.x;
    if (threadIdx.x < SLICE_SZ && a < A) {
        const unsigned long long* wv = &acc64[threadIdx.x * 3];
        float v[6];
        #pragma unroll
        for (int j = 0; j < 3; ++j) {
            unsigned long long x = wv[j];
            float n = (float)(unsigned int)(x >> 52);
            v[2 * j + 0] = (float)((double)(x & FIELD_MASK)         * Q) - n * 16.0f;
            v[2 * j + 1] = (float)((double)((x >> 26) & FIELD_MASK) * Q) - n * 16.0f;
        }

        float a0 = v[0], b0 = v[1];   // m=0 (y)
        float a1 = v[2], b1 = v[3];   // m=1 (z)
        float a2 = v[4], b2 = v[5];   // m=2 (x)

        float c0 = (a1 * b2 - a2 * b1) * INV_SQRT2;
        float c1 = (a2 * b0 - a0 * b2) * INV_SQRT2;
        float c2 = (a0 * b1 - a1 * b0) * INV_SQRT2;

        float* o = out + (size_t)a * 9;
        o[0] = a0; o[1] = b0; o[2] = c0;
        o[3] = a1; o[4] = b1; o[5] = c1;
        o[6] = a2; o[7] = b2; o[8] = c2;
    }
}

// ===========================================================================
// Fallback path (Round 6): packed fixed-point u64 global atomics. Used only
// if the workspace can't hold the sort payload.
// ===========================================================================
__global__ void edge_kernel_fb(const float* __restrict__ vecs,
                               const int* __restrict__ centers,
                               const int* __restrict__ neighbors,
                               const int* __restrict__ species,
                               const float* __restrict__ G,
                               unsigned long long* __restrict__ vacc, int E) {
    __shared__ float Gs[256];
    Gs[threadIdx.x] = G[threadIdx.x];
    __syncthreads();

    int e = blockIdx.x * blockDim.x + threadIdx.x;
    if (e >= E) return;

    float vx = vecs[3 * e + 0], vy = vecs[3 * e + 1], vz = vecs[3 * e + 2];
    int c = centers[e];
    int tc = species[c];
    int tn = species[neighbors[e]];
    const float* Gp = &Gs[((tc * 4 + tn) * 8) * 2];

    float pr[6];
    if (!edge_products(vx, vy, vz, Gp, pr)) return;

    unsigned long long* base = vacc + (size_t)c * 4;
    #pragma unroll
    for (int j = 0; j < 3; ++j) {
        float el = fminf(fmaxf(fmaf(pr[2 * j + 0], Q_INV, BIAS_ENC) + 0.5f, 0.0f), ENC_MAX);
        float eh = fminf(fmaxf(fmaf(pr[2 * j + 1], Q_INV, BIAS_ENC) + 0.5f, 0.0f), ENC_MAX);
        unsigned long long w = (1ULL << 52)
                             | ((unsigned long long)(unsigned int)eh << 26)
                             | (unsigned long long)(unsigned int)el;
        atomicAdd(base + j, w);
    }
}

__global__ void finalize_fb(const unsigned long long* __restrict__ vacc,
                            float* __restrict__ out, int A) {
    int a = blockIdx.x * blockDim.x + threadIdx.x;
    if (a >= A) return;

    const unsigned long long* w = vacc + (size_t)a * 4;
    double v[6];
    #pragma unroll
    for (int j = 0; j < 3; ++j) {
        unsigned long long x = w[j];
        double n = (double)(x >> 52);
        v[2 * j + 0] = (double)(x & FIELD_MASK)         * (double)Q - n * 16.0;
        v[2 * j + 1] = (double)((x >> 26) & FIELD_MASK) * (double)Q - n * 16.0;
    }
    float a0 = (float)v[0], b0 = (float)v[1];
    float a1 = (float)v[2], b1 = (float)v[3];
    float a2 = (float)v[4], b2 = (float)v[5];
    float c0 = (a1 * b2 - a2 * b1) * INV_SQRT2;
    float c1 = (a2 * b0 - a0 * b2) * INV_SQRT2;
    float c2 = (a0 * b1 - a1 * b0) * INV_SQRT2;
    float* o = out + (size_t)a * 9;
    o[0] = a0; o[1] = b0; o[2] = c0;
    o[3] = a1; o[4] = b1; o[5] = c1;
    o[6] = a2; o[7] = b2; o[8] = c2;
}

extern "C" void kernel_launch(void* const* d_in, const int* in_sizes, int n_in,
                              void* d_out, int out_size, void* d_ws, size_t ws_size,
                              hipStream_t stream) {
    const float* vecs      = (const float*)d_in[0];
    const float* W_species = (const float*)d_in[1];
    const float* Emb       = (const float*)d_in[2];
    const float* Wc        = (const float*)d_in[3];
    const int*   centers   = (const int*)d_in[4];
    const int*   neighbors = (const int*)d_in[5];
    const int*   species   = (const int*)d_in[6];

    int E = in_sizes[0] / 3;
    int A = in_sizes[6];

    int nslice = (A + SLICE_SZ - 1) / SLICE_SZ;

    // Workspace layout (sort path): payload | ghist | sliceStart | cursor | G
    size_t payloadBytes = (size_t)E * 8;   // 8B per entry
    size_t metaBytes    = (size_t)(3 * nslice + 1 + 256) * sizeof(float) + 256;
    bool sort_path = (nslice <= MAX_NSLICE) && (ws_size >= payloadBytes + metaBytes);

    if (sort_path) {
        unsigned long long* payload = (unsigned long long*)d_ws;
        unsigned int* ghist      = (unsigned int*)((char*)d_ws + payloadBytes);
        unsigned int* sliceStart = ghist + nslice;
        unsigned int* cursor     = sliceStart + (nslice + 1);
        float*        G          = (float*)(cursor + nslice);

        (void)hipMemsetAsync(ghist, 0, (size_t)nslice * sizeof(unsigned int), stream);
        build_G_kernel<<<1, 256, 0, stream>>>(W_species, Emb, Wc, G);

        int nbh = (E + HIST_EPB - 1) / HIST_EPB;
        hist_kernel<<<nbh, 256, 0, stream>>>(centers, ghist, E, nslice);
        scan_kernel<<<1, 64, 0, stream>>>(ghist, sliceStart, cursor, nslice);
        int nbs = (E + SCAT_EPB - 1) / SCAT_EPB;
        scatter_kernel<<<nbs, SCAT_THREADS, 0, stream>>>(
            vecs, centers, neighbors, species, cursor, payload, E, nslice);
        accum_kernel<<<nslice, ACC_THREADS, 0, stream>>>(
            payload, sliceStart, cursor, G, (float*)d_out, A);
    } else {
        unsigned long long* vacc = (unsigned long long*)d_ws;  // (A,4)
        float* G = (float*)(vacc + (size_t)A * 4);
        (void)hipMemsetAsync(vacc, 0, (size_t)A * 4 * sizeof(unsigned long long), stream);
        build_G_kernel<<<1, 256, 0, stream>>>(W_species, Emb, Wc, G);
        const int threads = 256;
        edge_kernel_fb<<<(E + threads - 1) / threads, threads, 0, stream>>>(
            vecs, centers, neighbors, species, G, vacc, E);
        finalize_fb<<<(A + threads - 1) / threads, threads, 0, stream>>>(
            vacc, (float*)d_out, A);
    }
}

// Round 14
// 51.178 us; speedup vs baseline: 3.6898x; 1.5226x over previous
//
#include <hip/hip_runtime.h>
#include <hip/hip_fp16.h>
#include <math.h>

#define N_RADIAL 8
#define N_PSEUDO 4
#define EMB_DIM 32
#define CUTOFF 5.0f
#define WIDTH 0.5f
#define SQRT3_4PI 0.48860251190291992f   /* sqrt(3/(4*pi)) */
#define INV_SQRT2 0.70710678118654752f
#define PI_F 3.14159265358979323846f

#define SLICE_SHIFT 7
#define SLICE_SZ 128            /* atoms per slice */
#define MAX_NSLICE 2048         /* LDS histogram capacity */
#define SCAT_EPB 8192           /* edges per block, scatter pass */
#define SCAT_THREADS 1024
#define SCAT_ITER (SCAT_EPB / SCAT_THREADS)   /* 8: register payload stash */
#define ACC_THREADS 1024

/* Fixed-point packing (proven R6/R13): q=2^-13, bias 16.
   word = [count:12 | e_hi:26 | e_lo:26]; per-edge add non-negative in every
   field -> no cross-field carries; capacity 4096 edges/atom. */
#define Q_INV 8192.0f
#define Q 1.220703125e-4
#define BIAS_ENC 131072.0f
#define ENC_MAX 262143.0f
#define FIELD_MASK 0x3FFFFFFULL

// ---------------------------------------------------------------------------
// Build G[tc][tn][n][k] (k=0,1 only — v[:,:,2] is discarded by the reference)
// AND init per-slice cursors to s*cap (fixed-capacity layout: no hist/scan).
// ---------------------------------------------------------------------------
__global__ void init_kernel(const float* __restrict__ W_species, // (4,4)
                            const float* __restrict__ Emb,       // (4,32)
                            const float* __restrict__ Wc,        // (32,3)
                            float* __restrict__ G,
                            unsigned int* __restrict__ cursor,
                            int nslice, int cap) {
    int i = threadIdx.x;            // 512 threads
    if (i < 256) {
        int k  = i & 1;
        int n  = (i >> 1) & 7;
        int tn = (i >> 4) & 3;
        int tc = i >> 6;
        float acc = 0.0f;
        #pragma unroll
        for (int q = 0; q < N_PSEUDO; ++q) {
            int d = n * N_PSEUDO + q;
            acc += W_species[tn * N_PSEUDO + q] * Emb[tc * EMB_DIM + d] * Wc[d * 3 + k];
        }
        G[i] = acc;
    }
    for (int s = i; s < nslice; s += (int)blockDim.x)
        cursor[s] = (unsigned int)(s * cap);
}

// ---------------------------------------------------------------------------
// Per-edge math, native trig (theta < pi: no range reduction needed).
// pr[j] = Y[m]*s[k] m-major: (Y0s0,Y0s1,Y1s0,Y1s1,Y2s0,Y2s1)
// ---------------------------------------------------------------------------
__device__ __forceinline__ bool edge_products(float vx, float vy, float vz,
                                              const float* __restrict__ Gp,
                                              float pr[6]) {
    float r = sqrtf(vx * vx + vy * vy + vz * vz);
    if (r >= CUTOFF) return false;

    float rinv = 1.0f / (r + 1e-10f);

    float t = fminf(fmaxf((r - (CUTOFF - WIDTH)) * (1.0f / WIDTH), 0.0f), 1.0f);
    float fcut = 0.5f * (1.0f + __cosf(PI_F * t));

    float theta = (PI_F / CUTOFF) * r;
    float s1 = __sinf(theta);
    float c1 = __cosf(theta);
    float twoc  = 2.0f * c1;
    float sn_m1 = 0.0f;
    float sn    = s1;

    float s0 = 0.0f, s1a = 0.0f;
    #pragma unroll
    for (int n = 0; n < N_RADIAL; ++n) {
        s0  = fmaf(sn, Gp[n * 2 + 0], s0);
        s1a = fmaf(sn, Gp[n * 2 + 1], s1a);
        float nxt = twoc * sn - sn_m1;
        sn_m1 = sn;
        sn = nxt;
    }
    float coef = rinv * fcut;
    s0 *= coef; s1a *= coef;

    float Y0 = SQRT3_4PI * vy * rinv;
    float Y1 = SQRT3_4PI * vz * rinv;
    float Y2 = SQRT3_4PI * vx * rinv;

    pr[0] = Y0 * s0; pr[1] = Y0 * s1a;
    pr[2] = Y1 * s0; pr[3] = Y1 * s1a;
    pr[4] = Y2 * s0; pr[5] = Y2 * s1a;
    return true;
}

// ---------------------------------------------------------------------------
// Scatter: single read pass stashes the 8B encoded payload (f16 vx,vy,vz +
// u16 meta{lid|tc<<7|tn<<9}) in registers + LDS count -> one cursor
// reservation per touched slice -> bounds-checked placement into the slice's
// fixed-capacity region. Normal stores (L2 merges; nt was 46B/store, R12).
// ---------------------------------------------------------------------------
__global__ __launch_bounds__(SCAT_THREADS)
void scatter_kernel(const float* __restrict__ vecs,
                    const int*   __restrict__ centers,
                    const int*   __restrict__ neighbors,
                    const int*   __restrict__ species,
                    unsigned int* __restrict__ cursor,
                    unsigned long long* __restrict__ payload, // 8B per entry
                    int E, int nslice, int cap) {
    __shared__ unsigned int hist[MAX_NSLICE];
    for (int i = threadIdx.x; i < nslice; i += blockDim.x) hist[i] = 0u;
    __syncthreads();

    int beg = blockIdx.x * SCAT_EPB;
    int end = min(beg + SCAT_EPB, E);

    unsigned long long word[SCAT_ITER];
    int sl[SCAT_ITER];

    // single read pass: predicate on r^2 (no sqrt), encode, LDS count
    #pragma unroll
    for (int k = 0; k < SCAT_ITER; ++k) {
        sl[k] = -1;
        word[k] = 0;
        int e = beg + k * SCAT_THREADS + (int)threadIdx.x;
        if (e < end) {
            float vx = vecs[3 * e + 0], vy = vecs[3 * e + 1], vz = vecs[3 * e + 2];
            float r2 = vx * vx + vy * vy + vz * vz;
            if (r2 < CUTOFF * CUTOFF) {
                int c = centers[e];
                unsigned int tc = (unsigned int)species[c];
                unsigned int tn = (unsigned int)species[neighbors[e]];
                unsigned int meta = (unsigned int)(c & (SLICE_SZ - 1)) | (tc << 7) | (tn << 9);
                unsigned int hx = (unsigned int)__half_as_ushort(__float2half(vx));
                unsigned int hy = (unsigned int)__half_as_ushort(__float2half(vy));
                unsigned int hz = (unsigned int)__half_as_ushort(__float2half(vz));
                unsigned int lo = hx | (hy << 16);
                unsigned int hi = hz | (meta << 16);
                word[k] = ((unsigned long long)hi << 32) | lo;
                sl[k] = c >> SLICE_SHIFT;
                atomicAdd(&hist[sl[k]], 1u);
            }
        }
    }
    __syncthreads();

    // reserve global ranges; hist[s] becomes this block's running cursor
    for (int s = threadIdx.x; s < nslice; s += (int)blockDim.x) {
        unsigned int c = hist[s];
        hist[s] = c ? atomicAdd(&cursor[s], c) : 0u;
    }
    __syncthreads();

    // placement from registers; bounds check guards slice-capacity overflow
    // (cap = mean + 8*sigma: overflow prob ~1e-13/slice)
    #pragma unroll
    for (int k = 0; k < SCAT_ITER; ++k) {
        if (sl[k] >= 0) {
            unsigned int pos = atomicAdd(&hist[sl[k]], 1u);
            if (pos < (unsigned int)((sl[k] + 1) * cap))
                payload[pos] = word[k];
        }
    }
}

// ---------------------------------------------------------------------------
// Accum: one block per slice. Contiguous 8B reads from [s*cap, cursor[s]),
// f16 decode, native-trig math, 3 native u64 LDS atomics per edge
// (ds_add_u64; f32 LDS atomicAdd was the hidden 84us CAS path, R13),
// fixed-point decode + cross product epilogue.
// ---------------------------------------------------------------------------
__global__ __launch_bounds__(ACC_THREADS)
void accum_kernel(const unsigned long long* __restrict__ payload,
                  const unsigned int* __restrict__ cursor,   // final = packed end
                  const float* __restrict__ G,
                  float* __restrict__ out, int A, int cap) {
    __shared__ float Gs[256];
    __shared__ unsigned long long acc64[SLICE_SZ * 3];
    int s = blockIdx.x;

    if (threadIdx.x < 256) Gs[threadIdx.x] = G[threadIdx.x];
    for (int i = threadIdx.x; i < SLICE_SZ * 3; i += blockDim.x) acc64[i] = 0ull;
    __syncthreads();

    unsigned int beg = (unsigned int)(s * cap);
    unsigned int end = min(cursor[s], (unsigned int)((s + 1) * cap));
    for (unsigned int i = beg + threadIdx.x; i < end; i += blockDim.x) {
        unsigned long long w = payload[i];
        unsigned int lo = (unsigned int)w;
        unsigned int hi = (unsigned int)(w >> 32);
        float vx = __half2float(__ushort_as_half((unsigned short)(lo & 0xffffu)));
        float vy = __half2float(__ushort_as_half((unsigned short)(lo >> 16)));
        float vz = __half2float(__ushort_as_half((unsigned short)(hi & 0xffffu)));
        unsigned int meta = hi >> 16;
        int lid = (int)(meta & (SLICE_SZ - 1));
        int tc  = (int)((meta >> 7) & 3);
        int tn  = (int)((meta >> 9) & 3);
        const float* Gp = &Gs[((tc * 4 + tn) * 8) * 2];

        float pr[6];
        if (!edge_products(vx, vy, vz, Gp, pr)) continue;  // f16-boundary: fcut~0

        unsigned long long* ap = &acc64[lid * 3];
        #pragma unroll
        for (int j = 0; j < 3; ++j) {
            float el = fminf(fmaxf(fmaf(pr[2 * j + 0], Q_INV, BIAS_ENC) + 0.5f, 0.0f), ENC_MAX);
            float eh = fminf(fmaxf(fmaf(pr[2 * j + 1], Q_INV, BIAS_ENC) + 0.5f, 0.0f), ENC_MAX);
            unsigned long long wrd = (1ULL << 52)
                                   | ((unsigned long long)(unsigned int)eh << 26)
                                   | (unsigned long long)(unsigned int)el;
            atomicAdd(ap + j, wrd);
        }
    }
    __syncthreads();

    int a = s * SLICE_SZ + (int)threadIdx.x;
    if (threadIdx.x < SLICE_SZ && a < A) {
        const unsigned long long* wv = &acc64[threadIdx.x * 3];
        float v[6];
        #pragma unroll
        for (int j = 0; j < 3; ++j) {
            unsigned long long x = wv[j];
            float n = (float)(unsigned int)(x >> 52);
            v[2 * j + 0] = (float)((double)(x & FIELD_MASK)         * Q) - n * 16.0f;
            v[2 * j + 1] = (float)((double)((x >> 26) & FIELD_MASK) * Q) - n * 16.0f;
        }

        float a0 = v[0], b0 = v[1];   // m=0 (y)
        float a1 = v[2], b1 = v[3];   // m=1 (z)
        float a2 = v[4], b2 = v[5];   // m=2 (x)

        float c0 = (a1 * b2 - a2 * b1) * INV_SQRT2;
        float c1 = (a2 * b0 - a0 * b2) * INV_SQRT2;
        float c2 = (a0 * b1 - a1 * b0) * INV_SQRT2;

        float* o = out + (size_t)a * 9;
        o[0] = a0; o[1] = b0; o[2] = c0;
        o[3] = a1; o[4] = b1; o[5] = c1;
        o[6] = a2; o[7] = b2; o[8] = c2;
    }
}

// ===========================================================================
// Fallback path (Round 6): packed fixed-point u64 global atomics. Used only
// if the workspace can't hold the fixed-capacity payload.
// ===========================================================================
__global__ void edge_kernel_fb(const float* __restrict__ vecs,
                               const int* __restrict__ centers,
                               const int* __restrict__ neighbors,
                               const int* __restrict__ species,
                               const float* __restrict__ G,
                               unsigned long long* __restrict__ vacc, int E) {
    __shared__ float Gs[256];
    Gs[threadIdx.x] = G[threadIdx.x];
    __syncthreads();

    int e = blockIdx.x * blockDim.x + threadIdx.x;
    if (e >= E) return;

    float vx = vecs[3 * e + 0], vy = vecs[3 * e + 1], vz = vecs[3 * e + 2];
    int c = centers[e];
    int tc = species[c];
    int tn = species[neighbors[e]];
    const float* Gp = &Gs[((tc * 4 + tn) * 8) * 2];

    float pr[6];
    if (!edge_products(vx, vy, vz, Gp, pr)) return;

    unsigned long long* base = vacc + (size_t)c * 4;
    #pragma unroll
    for (int j = 0; j < 3; ++j) {
        float el = fminf(fmaxf(fmaf(pr[2 * j + 0], Q_INV, BIAS_ENC) + 0.5f, 0.0f), ENC_MAX);
        float eh = fminf(fmaxf(fmaf(pr[2 * j + 1], Q_INV, BIAS_ENC) + 0.5f, 0.0f), ENC_MAX);
        unsigned long long w = (1ULL << 52)
                             | ((unsigned long long)(unsigned int)eh << 26)
                             | (unsigned long long)(unsigned int)el;
        atomicAdd(base + j, w);
    }
}

__global__ void finalize_fb(const unsigned long long* __restrict__ vacc,
                            float* __restrict__ out, int A) {
    int a = blockIdx.x * blockDim.x + threadIdx.x;
    if (a >= A) return;

    const unsigned long long* w = vacc + (size_t)a * 4;
    double v[6];
    #pragma unroll
    for (int j = 0; j < 3; ++j) {
        unsigned long long x = w[j];
        double n = (double)(x >> 52);
        v[2 * j + 0] = (double)(x & FIELD_MASK)         * (double)Q - n * 16.0;
        v[2 * j + 1] = (double)((x >> 26) & FIELD_MASK) * (double)Q - n * 16.0;
    }
    float a0 = (float)v[0], b0 = (float)v[1];
    float a1 = (float)v[2], b1 = (float)v[3];
    float a2 = (float)v[4], b2 = (float)v[5];
    float c0 = (a1 * b2 - a2 * b1) * INV_SQRT2;
    float c1 = (a2 * b0 - a0 * b2) * INV_SQRT2;
    float c2 = (a0 * b1 - a1 * b0) * INV_SQRT2;
    float* o = out + (size_t)a * 9;
    o[0] = a0; o[1] = b0; o[2] = c0;
    o[3] = a1; o[4] = b1; o[5] = c1;
    o[6] = a2; o[7] = b2; o[8] = c2;
}

extern "C" void kernel_launch(void* const* d_in, const int* in_sizes, int n_in,
                              void* d_out, int out_size, void* d_ws, size_t ws_size,
                              hipStream_t stream) {
    const float* vecs      = (const float*)d_in[0];
    const float* W_species = (const float*)d_in[1];
    const float* Emb       = (const float*)d_in[2];
    const float* Wc        = (const float*)d_in[3];
    const int*   centers   = (const int*)d_in[4];
    const int*   neighbors = (const int*)d_in[5];
    const int*   species   = (const int*)d_in[6];

    int E = in_sizes[0] / 3;
    int A = in_sizes[6];

    int nslice = (A + SLICE_SZ - 1) / SLICE_SZ;

    // Fixed per-slice capacity: mean + 8*sigma (multinomial tail ~1e-13),
    // rounded up to 64. Counts ALL edges (7% above passing count: extra slack).
    double mean = (double)E / (double)nslice;
    int cap = (int)((mean + 8.0 * sqrt(mean) + 63.0) / 64.0) * 64;

    // Workspace layout: payload (nslice*cap u64) | cursor | G
    size_t payloadBytes = (size_t)nslice * (size_t)cap * 8;
    size_t metaBytes    = (size_t)(nslice + 256) * sizeof(float) + 256;
    bool sort_path = (nslice <= MAX_NSLICE) && (ws_size >= payloadBytes + metaBytes);

    if (sort_path) {
        unsigned long long* payload = (unsigned long long*)d_ws;
        unsigned int* cursor = (unsigned int*)((char*)d_ws + payloadBytes);
        float*        G      = (float*)(cursor + nslice);

        init_kernel<<<1, 512, 0, stream>>>(W_species, Emb, Wc, G, cursor,
                                           nslice, cap);
        int nbs = (E + SCAT_EPB - 1) / SCAT_EPB;
        scatter_kernel<<<nbs, SCAT_THREADS, 0, stream>>>(
            vecs, centers, neighbors, species, cursor, payload, E, nslice, cap);
        accum_kernel<<<nslice, ACC_THREADS, 0, stream>>>(
            payload, cursor, G, (float*)d_out, A, cap);
    } else {
        unsigned long long* vacc = (unsigned long long*)d_ws;  // (A,4)
        float* G = (float*)(vacc + (size_t)A * 4);
        (void)hipMemsetAsync(vacc, 0, (size_t)A * 4 * sizeof(unsigned long long), stream);
        init_kernel<<<1, 512, 0, stream>>>(W_species, Emb, Wc, G,
                                           (unsigned int*)G, 0, 0);
        const int threads = 256;
        edge_kernel_fb<<<(E + threads - 1) / threads, threads, 0, stream>>>(
            vecs, centers, neighbors, species, G, vacc, E);
        finalize_fb<<<(A + threads - 1) / threads, threads, 0, stream>>>(
            vacc, (float*)d_out, A);
    }
}

// Round 15
// 48.742 us; speedup vs baseline: 3.8741x; 1.0500x over previous
//
#include <hip/hip_runtime.h>
#include <hip/hip_fp16.h>
#include <math.h>

#define N_RADIAL 8
#define N_PSEUDO 4
#define EMB_DIM 32
#define CUTOFF 5.0f
#define WIDTH 0.5f
#define SQRT3_4PI 0.48860251190291992f   /* sqrt(3/(4*pi)) */
#define INV_SQRT2 0.70710678118654752f
#define PI_F 3.14159265358979323846f

#define SLICE_SHIFT 8
#define SLICE_SZ 256            /* atoms per slice (halves cursor reservations) */
#define MAX_NSLICE 2048         /* LDS histogram capacity */
#define SCAT_EPB 8192           /* edges per block, scatter pass */
#define SCAT_THREADS 1024
#define SCAT_ITER (SCAT_EPB / SCAT_THREADS)   /* 8: register payload stash */
#define ACC_THREADS 1024
#define MAX_SPEC_WORDS 4096     /* 2-bit packed species: supports A <= 65536 */

/* Fixed-point packing (proven R6/R13): q=2^-13, bias 16.
   word = [count:12 | e_hi:26 | e_lo:26]; per-edge add non-negative in every
   field -> no cross-field carries; capacity 4096 edges/atom. */
#define Q_INV 8192.0f
#define Q 1.220703125e-4
#define BIAS_ENC 131072.0f
#define ENC_MAX 262143.0f
#define FIELD_MASK 0x3FFFFFFULL

// ---------------------------------------------------------------------------
// Init: block 0 builds G[tc][tn][n][k] (k=0,1) + per-slice cursors (s*cap);
// all blocks pack species into 2-bit words (16 atoms per u32).
// ---------------------------------------------------------------------------
__global__ void init_kernel(const float* __restrict__ W_species, // (4,4)
                            const float* __restrict__ Emb,       // (4,32)
                            const float* __restrict__ Wc,        // (32,3)
                            const int*   __restrict__ species,   // (A,)
                            float* __restrict__ G,
                            unsigned int* __restrict__ cursor,
                            unsigned int* __restrict__ spec_packed,
                            int A, int nslice, int cap, int words) {
    int tid = blockIdx.x * blockDim.x + threadIdx.x;

    if (blockIdx.x == 0) {
        int i = threadIdx.x;
        if (i < 256) {
            int k  = i & 1;
            int n  = (i >> 1) & 7;
            int tn = (i >> 4) & 3;
            int tc = i >> 6;
            float acc = 0.0f;
            #pragma unroll
            for (int q = 0; q < N_PSEUDO; ++q) {
                int d = n * N_PSEUDO + q;
                acc += W_species[tn * N_PSEUDO + q] * Emb[tc * EMB_DIM + d] * Wc[d * 3 + k];
            }
            G[i] = acc;
        }
        for (int s = i; s < nslice; s += (int)blockDim.x)
            cursor[s] = (unsigned int)(s * cap);
    }

    for (int w = tid; w < words; w += (int)(gridDim.x * blockDim.x)) {
        unsigned int v = 0;
        int base = w * 16;
        #pragma unroll
        for (int j = 0; j < 16; ++j) {
            int a = base + j;
            if (a < A) v |= ((unsigned int)species[a] & 3u) << (2 * j);
        }
        spec_packed[w] = v;
    }
}

// ---------------------------------------------------------------------------
// Per-edge math, native trig (theta < pi: no range reduction needed).
// pr[j] = Y[m]*s[k] m-major: (Y0s0,Y0s1,Y1s0,Y1s1,Y2s0,Y2s1)
// ---------------------------------------------------------------------------
__device__ __forceinline__ bool edge_products(float vx, float vy, float vz,
                                              const float* __restrict__ Gp,
                                              float pr[6]) {
    float r = sqrtf(vx * vx + vy * vy + vz * vz);
    if (r >= CUTOFF) return false;

    float rinv = 1.0f / (r + 1e-10f);

    float t = fminf(fmaxf((r - (CUTOFF - WIDTH)) * (1.0f / WIDTH), 0.0f), 1.0f);
    float fcut = 0.5f * (1.0f + __cosf(PI_F * t));

    float theta = (PI_F / CUTOFF) * r;
    float s1 = __sinf(theta);
    float c1 = __cosf(theta);
    float twoc  = 2.0f * c1;
    float sn_m1 = 0.0f;
    float sn    = s1;

    float s0 = 0.0f, s1a = 0.0f;
    #pragma unroll
    for (int n = 0; n < N_RADIAL; ++n) {
        s0  = fmaf(sn, Gp[n * 2 + 0], s0);
        s1a = fmaf(sn, Gp[n * 2 + 1], s1a);
        float nxt = twoc * sn - sn_m1;
        sn_m1 = sn;
        sn = nxt;
    }
    float coef = rinv * fcut;
    s0 *= coef; s1a *= coef;

    float Y0 = SQRT3_4PI * vy * rinv;
    float Y1 = SQRT3_4PI * vz * rinv;
    float Y2 = SQRT3_4PI * vx * rinv;

    pr[0] = Y0 * s0; pr[1] = Y0 * s1a;
    pr[2] = Y1 * s0; pr[3] = Y1 * s1a;
    pr[4] = Y2 * s0; pr[5] = Y2 * s1a;
    return true;
}

// ---------------------------------------------------------------------------
// Scatter: species lookups from a 2-bit LDS table (no random global gathers),
// register payload stash, one cursor reservation per touched slice,
// bounds-checked placement. Normal stores (nt refuted in R12).
// LDSSPEC=false falls back to global packed-table lookups (A > 65536).
// ---------------------------------------------------------------------------
template <bool LDSSPEC>
__global__ __launch_bounds__(SCAT_THREADS)
void scatter_kernel(const float* __restrict__ vecs,
                    const int*   __restrict__ centers,
                    const int*   __restrict__ neighbors,
                    const unsigned int* __restrict__ spec_packed,
                    unsigned int* __restrict__ cursor,
                    unsigned long long* __restrict__ payload, // 8B per entry
                    int E, int nslice, int cap, int words) {
    __shared__ unsigned int hist[MAX_NSLICE];
    __shared__ unsigned int spec[LDSSPEC ? MAX_SPEC_WORDS : 1];

    for (int i = threadIdx.x; i < nslice; i += blockDim.x) hist[i] = 0u;
    if constexpr (LDSSPEC) {
        for (int i = threadIdx.x; i < words; i += blockDim.x)
            spec[i] = spec_packed[i];
    }
    __syncthreads();

    int beg = blockIdx.x * SCAT_EPB;
    int end = min(beg + SCAT_EPB, E);

    unsigned long long word[SCAT_ITER];
    int sl[SCAT_ITER];

    // single read pass: predicate on r^2 (no sqrt), encode, LDS count
    #pragma unroll
    for (int k = 0; k < SCAT_ITER; ++k) {
        sl[k] = -1;
        word[k] = 0;
        int e = beg + k * SCAT_THREADS + (int)threadIdx.x;
        if (e < end) {
            float vx = vecs[3 * e + 0], vy = vecs[3 * e + 1], vz = vecs[3 * e + 2];
            float r2 = vx * vx + vy * vy + vz * vz;
            if (r2 < CUTOFF * CUTOFF) {
                int c  = centers[e];
                int nb = neighbors[e];
                unsigned int tc, tn;
                if constexpr (LDSSPEC) {
                    tc = (spec[c >> 4]  >> ((c & 15) << 1)) & 3u;
                    tn = (spec[nb >> 4] >> ((nb & 15) << 1)) & 3u;
                } else {
                    tc = (spec_packed[c >> 4]  >> ((c & 15) << 1)) & 3u;
                    tn = (spec_packed[nb >> 4] >> ((nb & 15) << 1)) & 3u;
                }
                unsigned int meta = (unsigned int)(c & (SLICE_SZ - 1)) | (tc << 8) | (tn << 10);
                unsigned int hx = (unsigned int)__half_as_ushort(__float2half(vx));
                unsigned int hy = (unsigned int)__half_as_ushort(__float2half(vy));
                unsigned int hz = (unsigned int)__half_as_ushort(__float2half(vz));
                unsigned int lo = hx | (hy << 16);
                unsigned int hi = hz | (meta << 16);
                word[k] = ((unsigned long long)hi << 32) | lo;
                sl[k] = c >> SLICE_SHIFT;
                atomicAdd(&hist[sl[k]], 1u);
            }
        }
    }
    __syncthreads();

    // reserve global ranges; hist[s] becomes this block's running cursor
    for (int s = threadIdx.x; s < nslice; s += (int)blockDim.x) {
        unsigned int c = hist[s];
        hist[s] = c ? atomicAdd(&cursor[s], c) : 0u;
    }
    __syncthreads();

    // placement from registers; bounds check guards slice-capacity overflow
    // (cap = mean + 8*sigma: overflow prob ~1e-13/slice)
    #pragma unroll
    for (int k = 0; k < SCAT_ITER; ++k) {
        if (sl[k] >= 0) {
            unsigned int pos = atomicAdd(&hist[sl[k]], 1u);
            if (pos < (unsigned int)((sl[k] + 1) * cap))
                payload[pos] = word[k];
        }
    }
}

// ---------------------------------------------------------------------------
// Accum: one block per slice. Contiguous 8B reads from [s*cap, cursor[s]),
// f16 decode, native-trig math, 3 native u64 LDS atomics per edge
// (ds_add_u64; f32 LDS atomicAdd is a slow CAS path — R13 finding),
// fixed-point decode + cross product epilogue.
// ---------------------------------------------------------------------------
__global__ __launch_bounds__(ACC_THREADS)
void accum_kernel(const unsigned long long* __restrict__ payload,
                  const unsigned int* __restrict__ cursor,   // final = packed end
                  const float* __restrict__ G,
                  float* __restrict__ out, int A, int cap) {
    __shared__ float Gs[256];
    __shared__ unsigned long long acc64[SLICE_SZ * 3];
    int s = blockIdx.x;

    if (threadIdx.x < 256) Gs[threadIdx.x] = G[threadIdx.x];
    for (int i = threadIdx.x; i < SLICE_SZ * 3; i += blockDim.x) acc64[i] = 0ull;
    __syncthreads();

    unsigned int beg = (unsigned int)(s * cap);
    unsigned int end = min(cursor[s], (unsigned int)((s + 1) * cap));
    for (unsigned int i = beg + threadIdx.x; i < end; i += blockDim.x) {
        unsigned long long w = payload[i];
        unsigned int lo = (unsigned int)w;
        unsigned int hi = (unsigned int)(w >> 32);
        float vx = __half2float(__ushort_as_half((unsigned short)(lo & 0xffffu)));
        float vy = __half2float(__ushort_as_half((unsigned short)(lo >> 16)));
        float vz = __half2float(__ushort_as_half((unsigned short)(hi & 0xffffu)));
        unsigned int meta = hi >> 16;
        int lid = (int)(meta & (SLICE_SZ - 1));
        int tc  = (int)((meta >> 8) & 3);
        int tn  = (int)((meta >> 10) & 3);
        const float* Gp = &Gs[((tc * 4 + tn) * 8) * 2];

        float pr[6];
        if (!edge_products(vx, vy, vz, Gp, pr)) continue;  // f16-boundary: fcut~0

        unsigned long long* ap = &acc64[lid * 3];
        #pragma unroll
        for (int j = 0; j < 3; ++j) {
            float el = fminf(fmaxf(fmaf(pr[2 * j + 0], Q_INV, BIAS_ENC) + 0.5f, 0.0f), ENC_MAX);
            float eh = fminf(fmaxf(fmaf(pr[2 * j + 1], Q_INV, BIAS_ENC) + 0.5f, 0.0f), ENC_MAX);
            unsigned long long wrd = (1ULL << 52)
                                   | ((unsigned long long)(unsigned int)eh << 26)
                                   | (unsigned long long)(unsigned int)el;
            atomicAdd(ap + j, wrd);
        }
    }
    __syncthreads();

    for (int lid = threadIdx.x; lid < SLICE_SZ; lid += (int)blockDim.x) {
        int a = s * SLICE_SZ + lid;
        if (a >= A) break;
        const unsigned long long* wv = &acc64[lid * 3];
        float v[6];
        #pragma unroll
        for (int j = 0; j < 3; ++j) {
            unsigned long long x = wv[j];
            float n = (float)(unsigned int)(x >> 52);
            v[2 * j + 0] = (float)((double)(x & FIELD_MASK)         * Q) - n * 16.0f;
            v[2 * j + 1] = (float)((double)((x >> 26) & FIELD_MASK) * Q) - n * 16.0f;
        }

        float a0 = v[0], b0 = v[1];   // m=0 (y)
        float a1 = v[2], b1 = v[3];   // m=1 (z)
        float a2 = v[4], b2 = v[5];   // m=2 (x)

        float c0 = (a1 * b2 - a2 * b1) * INV_SQRT2;
        float c1 = (a2 * b0 - a0 * b2) * INV_SQRT2;
        float c2 = (a0 * b1 - a1 * b0) * INV_SQRT2;

        float* o = out + (size_t)a * 9;
        o[0] = a0; o[1] = b0; o[2] = c0;
        o[3] = a1; o[4] = b1; o[5] = c1;
        o[6] = a2; o[7] = b2; o[8] = c2;
    }
}

// ===========================================================================
// Fallback path (Round 6): packed fixed-point u64 global atomics. Used only
// if the workspace can't hold the fixed-capacity payload.
// ===========================================================================
__global__ void edge_kernel_fb(const float* __restrict__ vecs,
                               const int* __restrict__ centers,
                               const int* __restrict__ neighbors,
                               const int* __restrict__ species,
                               const float* __restrict__ G,
                               unsigned long long* __restrict__ vacc, int E) {
    __shared__ float Gs[256];
    Gs[threadIdx.x] = G[threadIdx.x];
    __syncthreads();

    int e = blockIdx.x * blockDim.x + threadIdx.x;
    if (e >= E) return;

    float vx = vecs[3 * e + 0], vy = vecs[3 * e + 1], vz = vecs[3 * e + 2];
    int c = centers[e];
    int tc = species[c];
    int tn = species[neighbors[e]];
    const float* Gp = &Gs[((tc * 4 + tn) * 8) * 2];

    float pr[6];
    if (!edge_products(vx, vy, vz, Gp, pr)) return;

    unsigned long long* base = vacc + (size_t)c * 4;
    #pragma unroll
    for (int j = 0; j < 3; ++j) {
        float el = fminf(fmaxf(fmaf(pr[2 * j + 0], Q_INV, BIAS_ENC) + 0.5f, 0.0f), ENC_MAX);
        float eh = fminf(fmaxf(fmaf(pr[2 * j + 1], Q_INV, BIAS_ENC) + 0.5f, 0.0f), ENC_MAX);
        unsigned long long w = (1ULL << 52)
                             | ((unsigned long long)(unsigned int)eh << 26)
                             | (unsigned long long)(unsigned int)el;
        atomicAdd(base + j, w);
    }
}

__global__ void finalize_fb(const unsigned long long* __restrict__ vacc,
                            float* __restrict__ out, int A) {
    int a = blockIdx.x * blockDim.x + threadIdx.x;
    if (a >= A) return;

    const unsigned long long* w = vacc + (size_t)a * 4;
    double v[6];
    #pragma unroll
    for (int j = 0; j < 3; ++j) {
        unsigned long long x = w[j];
        double n = (double)(x >> 52);
        v[2 * j + 0] = (double)(x & FIELD_MASK)         * (double)Q - n * 16.0;
        v[2 * j + 1] = (double)((x >> 26) & FIELD_MASK) * (double)Q - n * 16.0;
    }
    float a0 = (float)v[0], b0 = (float)v[1];
    float a1 = (float)v[2], b1 = (float)v[3];
    float a2 = (float)v[4], b2 = (float)v[5];
    float c0 = (a1 * b2 - a2 * b1) * INV_SQRT2;
    float c1 = (a2 * b0 - a0 * b2) * INV_SQRT2;
    float c2 = (a0 * b1 - a1 * b0) * INV_SQRT2;
    float* o = out + (size_t)a * 9;
    o[0] = a0; o[1] = b0; o[2] = c0;
    o[3] = a1; o[4] = b1; o[5] = c1;
    o[6] = a2; o[7] = b2; o[8] = c2;
}

extern "C" void kernel_launch(void* const* d_in, const int* in_sizes, int n_in,
                              void* d_out, int out_size, void* d_ws, size_t ws_size,
                              hipStream_t stream) {
    const float* vecs      = (const float*)d_in[0];
    const float* W_species = (const float*)d_in[1];
    const float* Emb       = (const float*)d_in[2];
    const float* Wc        = (const float*)d_in[3];
    const int*   centers   = (const int*)d_in[4];
    const int*   neighbors = (const int*)d_in[5];
    const int*   species   = (const int*)d_in[6];

    int E = in_sizes[0] / 3;
    int A = in_sizes[6];

    int nslice = (A + SLICE_SZ - 1) / SLICE_SZ;
    int words  = (A + 15) / 16;

    // Fixed per-slice capacity: mean + 8*sigma (multinomial tail ~1e-13),
    // rounded up to 64. Counts ALL edges (7% above passing: extra slack).
    double mean = (double)E / (double)nslice;
    int cap = (int)((mean + 8.0 * sqrt(mean) + 63.0) / 64.0) * 64;

    // Workspace: payload (nslice*cap u64) | cursor | G | spec_packed
    size_t payloadBytes = (size_t)nslice * (size_t)cap * 8;
    size_t metaBytes    = ((size_t)nslice + 256 + (size_t)words) * 4 + 256;
    bool sort_path = (nslice <= MAX_NSLICE) && (ws_size >= payloadBytes + metaBytes);

    if (sort_path) {
        unsigned long long* payload = (unsigned long long*)d_ws;
        unsigned int* cursor = (unsigned int*)((char*)d_ws + payloadBytes);
        float*        G      = (float*)(cursor + nslice);
        unsigned int* spec_packed = (unsigned int*)(G + 256);

        int nbi = max(1, (words + 1023) / 1024);
        init_kernel<<<nbi, 1024, 0, stream>>>(W_species, Emb, Wc, species,
                                              G, cursor, spec_packed,
                                              A, nslice, cap, words);
        int nbs = (E + SCAT_EPB - 1) / SCAT_EPB;
        if (words <= MAX_SPEC_WORDS) {
            scatter_kernel<true><<<nbs, SCAT_THREADS, 0, stream>>>(
                vecs, centers, neighbors, spec_packed, cursor, payload,
                E, nslice, cap, words);
        } else {
            scatter_kernel<false><<<nbs, SCAT_THREADS, 0, stream>>>(
                vecs, centers, neighbors, spec_packed, cursor, payload,
                E, nslice, cap, words);
        }
        accum_kernel<<<nslice, ACC_THREADS, 0, stream>>>(
            payload, cursor, G, (float*)d_out, A, cap);
    } else {
        unsigned long long* vacc = (unsigned long long*)d_ws;  // (A,4)
        float* G = (float*)(vacc + (size_t)A * 4);
        unsigned int* cursor_dummy = (unsigned int*)(G + 256);
        (void)hipMemsetAsync(vacc, 0, (size_t)A * 4 * sizeof(unsigned long long), stream);
        init_kernel<<<1, 1024, 0, stream>>>(W_species, Emb, Wc, species,
                                            G, cursor_dummy, cursor_dummy,
                                            0, 0, 0, 0);
        const int threads = 256;
        edge_kernel_fb<<<(E + threads - 1) / threads, threads, 0, stream>>>(
            vecs, centers, neighbors, species, G, vacc, E);
        finalize_fb<<<(A + threads - 1) / threads, threads, 0, stream>>>(
            vacc, (float*)d_out, A);
    }
}